// Round 1
// baseline (6709.299 us; speedup 1.0000x reference)
//
#include <hip/hip_runtime.h>
#include <math.h>

#define B_ 4
#define R_ 1024
#define G_ 8
#define E_ 192
#define H_ 6
#define D_ 32
#define L_ 4
#define F_ 384
#define M_ (B_*R_*G_)              // 32768 rows
static const size_t NBUF = (size_t)M_ * E_;   // 6291456 floats per activation buffer

__device__ __forceinline__ float gelu_exact(float x) {
    return 0.5f * x * (1.0f + erff(x * 0.7071067811865475f));
}

// C[M,N] = act(A[M,K] @ W[K,N]) + Cres   (Cres may be null; act: 0 none, 1 exact-GELU)
// Requires M%64==0, N%64==0, K%16==0. Block 256 threads, 64x64 tile, 4x4 per thread.
__global__ __launch_bounds__(256)
void k_gemm(const float* __restrict__ A, const float* __restrict__ W,
            const float* __restrict__ Cres, float* __restrict__ C,
            int N, int K, int act)
{
    __shared__ float As[16][65];
    __shared__ float Bs[16][65];
    const int m0 = blockIdx.x * 64;
    const int n0 = blockIdx.y * 64;
    const int tid = threadIdx.x;
    const int tx = tid & 15, ty = tid >> 4;
    const int arow = tid >> 2, ac4 = (tid & 3) << 2;
    const int brow = tid >> 4, bc4 = (tid & 15) << 2;
    float acc[4][4] = {};
    for (int k0 = 0; k0 < K; k0 += 16) {
        float4 a4 = *(const float4*)(A + (size_t)(m0 + arow) * K + (k0 + ac4));
        float4 b4 = *(const float4*)(W + (size_t)(k0 + brow) * N + (n0 + bc4));
        As[ac4 + 0][arow] = a4.x; As[ac4 + 1][arow] = a4.y;
        As[ac4 + 2][arow] = a4.z; As[ac4 + 3][arow] = a4.w;
        Bs[brow][bc4 + 0] = b4.x; Bs[brow][bc4 + 1] = b4.y;
        Bs[brow][bc4 + 2] = b4.z; Bs[brow][bc4 + 3] = b4.w;
        __syncthreads();
#pragma unroll
        for (int kk = 0; kk < 16; ++kk) {
            float a[4], b[4];
#pragma unroll
            for (int i = 0; i < 4; ++i) a[i] = As[kk][ty * 4 + i];
#pragma unroll
            for (int j = 0; j < 4; ++j) b[j] = Bs[kk][tx * 4 + j];
#pragma unroll
            for (int i = 0; i < 4; ++i)
#pragma unroll
                for (int j = 0; j < 4; ++j)
                    acc[i][j] += a[i] * b[j];
        }
        __syncthreads();
    }
#pragma unroll
    for (int i = 0; i < 4; ++i) {
        const int m = m0 + ty * 4 + i;
        const size_t off = (size_t)m * N + (n0 + tx * 4);
        float v0 = acc[i][0], v1 = acc[i][1], v2 = acc[i][2], v3 = acc[i][3];
        if (act) { v0 = gelu_exact(v0); v1 = gelu_exact(v1);
                   v2 = gelu_exact(v2); v3 = gelu_exact(v3); }
        if (Cres) {
            float4 r4 = *(const float4*)(Cres + off);
            v0 += r4.x; v1 += r4.y; v2 += r4.z; v3 += r4.w;
        }
        float4 o4; o4.x = v0; o4.y = v1; o4.z = v2; o4.w = v3;
        *(float4*)(C + off) = o4;
    }
}

// Feature-group attention: 4096 seqs of length G=8, H=6 heads, D=32.
// One wave per (seq, head). lane = i*8+j: computes S[i][j], then O[i][j*4..j*4+3].
__global__ __launch_bounds__(256)
void k_attn1(const float* __restrict__ Q, const float* __restrict__ K,
             const float* __restrict__ V, float* __restrict__ T)
{
    const int wave = blockIdx.x * 4 + (threadIdx.x >> 6);
    const int lane = threadIdx.x & 63;
    const int seq = wave / H_;
    const int h = wave % H_;
    const int i = lane >> 3, j = lane & 7;
    const float4* qp = (const float4*)(Q + ((size_t)(seq * G_ + i)) * E_ + h * D_);
    const float4* kp = (const float4*)(K + ((size_t)(seq * G_ + j)) * E_ + h * D_);
    float s = 0.f;
#pragma unroll
    for (int d4 = 0; d4 < 8; ++d4) {
        float4 qv = qp[d4], kv = kp[d4];
        s += qv.x * kv.x + qv.y * kv.y + qv.z * kv.z + qv.w * kv.w;
    }
    s *= 0.17677669529663687f;  // 1/sqrt(32)
    float mx = s;
#pragma unroll
    for (int off = 1; off < 8; off <<= 1) mx = fmaxf(mx, __shfl_xor(mx, off));
    float p = __expf(s - mx);
    float sum = p;
#pragma unroll
    for (int off = 1; off < 8; off <<= 1) sum += __shfl_xor(sum, off);
    p /= sum;
    const int base = lane & ~7;
    float o0 = 0.f, o1 = 0.f, o2 = 0.f, o3 = 0.f;
#pragma unroll
    for (int jj = 0; jj < 8; ++jj) {
        float pj = __shfl(p, base + jj);
        const float4 vv = *(const float4*)(V + ((size_t)(seq * G_ + jj)) * E_ + h * D_ + j * 4);
        o0 += pj * vv.x; o1 += pj * vv.y; o2 += pj * vv.z; o3 += pj * vv.w;
    }
    float4 ov; ov.x = o0; ov.y = o1; ov.z = o2; ov.w = o3;
    *(float4*)(T + ((size_t)(seq * G_ + i)) * E_ + h * D_ + j * 4) = ov;
}

// Row attention (XR layout: row = s*R + r, s in [0,32)). One thread per q-row.
// Keys/values: rows [0, sep) of the same seq; key head = h if r < sep else 0.
__global__ __launch_bounds__(256)
void k_attn2(const float* __restrict__ Q, const float* __restrict__ K,
             const float* __restrict__ V, float* __restrict__ T,
             const int* __restrict__ sep_ptr)
{
    const int sep = *sep_ptr;
    const int sh = blockIdx.x >> 2;
    const int tile = blockIdx.x & 3;
    const int s = sh / H_, h = sh % H_;
    const int r = tile * 256 + threadIdx.x;
    const size_t qrow = (size_t)s * R_ + r;
    float4 q4[8];
    const float4* qp = (const float4*)(Q + qrow * E_ + h * D_);
#pragma unroll
    for (int d4 = 0; d4 < 8; ++d4) q4[d4] = qp[d4];
    const int hk = (r < sep) ? h : 0;
    const float* Kb = K + (size_t)s * R_ * E_ + hk * D_;
    const float* Vb = V + (size_t)s * R_ * E_ + hk * D_;
    float m = -1e30f, l = 0.f;
    float4 o4[8];
#pragma unroll
    for (int d4 = 0; d4 < 8; ++d4) { o4[d4].x = 0.f; o4[d4].y = 0.f; o4[d4].z = 0.f; o4[d4].w = 0.f; }
    for (int jkey = 0; jkey < sep; ++jkey) {
        const float4* kp = (const float4*)(Kb + (size_t)jkey * E_);
        float sc = 0.f;
#pragma unroll
        for (int d4 = 0; d4 < 8; ++d4) {
            float4 kv = kp[d4];
            sc += q4[d4].x * kv.x + q4[d4].y * kv.y + q4[d4].z * kv.z + q4[d4].w * kv.w;
        }
        sc *= 0.17677669529663687f;
        if (sc > m) {               // rare rescale (amortized flash update)
            float corr = __expf(m - sc);
            l *= corr;
#pragma unroll
            for (int d4 = 0; d4 < 8; ++d4) {
                o4[d4].x *= corr; o4[d4].y *= corr; o4[d4].z *= corr; o4[d4].w *= corr;
            }
            m = sc;
        }
        float p = __expf(sc - m);
        l += p;
        const float4* vp = (const float4*)(Vb + (size_t)jkey * E_);
#pragma unroll
        for (int d4 = 0; d4 < 8; ++d4) {
            float4 vv = vp[d4];
            o4[d4].x += p * vv.x; o4[d4].y += p * vv.y;
            o4[d4].z += p * vv.z; o4[d4].w += p * vv.w;
        }
    }
    const float inv = 1.f / l;
    float4* tp = (float4*)(T + qrow * E_ + h * D_);
#pragma unroll
    for (int d4 = 0; d4 < 8; ++d4) {
        float4 ov; ov.x = o4[d4].x * inv; ov.y = o4[d4].y * inv;
        ov.z = o4[d4].z * inv; ov.w = o4[d4].w * inv;
        tp[d4] = ov;
    }
}

// RMSNorm over last dim (192) with optional layout transpose.
// mode 0: in rows are X layout ((b*R+r)*G+g) -> out rows XR layout ((b*G+g)*R+r)
// mode 1: in rows are XR layout -> out rows X layout
// mode 2: same layout
__global__ __launch_bounds__(256)
void k_rms(const float* __restrict__ In, const float* __restrict__ g,
           float* __restrict__ Out, int mode)
{
    const int row = blockIdx.x * 4 + (threadIdx.x >> 6);
    const int lane = threadIdx.x & 63;
    const float* ip = In + (size_t)row * E_;
    float v0 = ip[lane], v1 = ip[lane + 64], v2 = ip[lane + 128];
    float ss = v0 * v0 + v1 * v1 + v2 * v2;
#pragma unroll
    for (int off = 32; off > 0; off >>= 1) ss += __shfl_xor(ss, off);
    const float inv = rsqrtf(ss * (1.0f / 192.0f) + 1.1920929e-07f);
    size_t orow;
    if (mode == 0) {
        const int b = row / (R_ * G_);
        const int r = (row / G_) % R_;
        const int gg = row % G_;
        orow = ((size_t)(b * G_ + gg)) * R_ + r;
    } else if (mode == 1) {
        const int b = row / (G_ * R_);
        const int gg = (row / R_) % G_;
        const int r = row % R_;
        orow = ((size_t)(b * R_ + r)) * G_ + gg;
    } else {
        orow = row;
    }
    float* op = Out + orow * E_;
    op[lane]       = v0 * inv * g[lane];
    op[lane + 64]  = v1 * inv * g[lane + 64];
    op[lane + 128] = v2 * inv * g[lane + 128];
}

extern "C" void kernel_launch(void* const* d_in, const int* in_sizes, int n_in,
                              void* d_out, int out_size, void* d_ws, size_t ws_size,
                              hipStream_t stream) {
    const float* hidden = (const float*)d_in[0];
    const float* Wq1 = (const float*)d_in[1];
    const float* Wk1 = (const float*)d_in[2];
    const float* Wv1 = (const float*)d_in[3];
    const float* Wo1 = (const float*)d_in[4];
    const float* Wq2 = (const float*)d_in[5];
    const float* Wk2 = (const float*)d_in[6];
    const float* Wv2 = (const float*)d_in[7];
    const float* Wo2 = (const float*)d_in[8];
    const float* W1  = (const float*)d_in[9];
    const float* W2  = (const float*)d_in[10];
    const float* g1  = (const float*)d_in[11];
    const float* g2  = (const float*)d_in[12];
    const float* g3  = (const float*)d_in[13];
    const int*   sep = (const int*)d_in[14];

    float* X  = (float*)d_out;          // activation in X layout; final result lives here
    float* ws = (float*)d_ws;
    float* Y  = ws;                     // XR-layout activation
    float* Qb = ws + NBUF;
    float* Kb = ws + 2 * NBUF;
    float* Vb = ws + 3 * NBUF;
    float* Tb = ws + 4 * NBUF;
    float* H1 = Qb;                     // MLP hidden [32768,384] aliases Qb+Kb

    const dim3 blk(256);
    const dim3 gE(M_ / 64, E_ / 64);    // 512 x 3
    const dim3 gF(M_ / 64, F_ / 64);    // 512 x 6
    const dim3 gA1((4096 * H_) / 4);    // attn1: 4 waves/block
    const dim3 gA2(32 * H_ * 4);        // attn2: (s,h) x 4 row-tiles of 256
    const dim3 gR(M_ / 4);              // rms: 4 waves/block, one row/wave

    for (int i = 0; i < L_; ++i) {
        const float* Xin = (i == 0) ? hidden : X;
        const size_t wE = (size_t)i * E_ * E_;
        const size_t wF = (size_t)i * E_ * F_;
        // --- feature-group attention ---
        k_gemm<<<gE, blk, 0, stream>>>(Xin, Wq1 + wE, nullptr, Qb, E_, E_, 0);
        k_gemm<<<gE, blk, 0, stream>>>(Xin, Wk1 + wE, nullptr, Kb, E_, E_, 0);
        k_gemm<<<gE, blk, 0, stream>>>(Xin, Wv1 + wE, nullptr, Vb, E_, E_, 0);
        k_attn1<<<gA1, blk, 0, stream>>>(Qb, Kb, Vb, Tb);
        k_gemm<<<gE, blk, 0, stream>>>(Tb, Wo1 + wE, Xin, X, E_, E_, 0);
        k_rms<<<gR, blk, 0, stream>>>(X, g1 + (size_t)i * E_, Y, 0);
        // --- row attention (train/test split; test rows use head-0 K/V) ---
        k_gemm<<<gE, blk, 0, stream>>>(Y, Wq2 + wE, nullptr, Qb, E_, E_, 0);
        k_gemm<<<gE, blk, 0, stream>>>(Y, Wk2 + wE, nullptr, Kb, E_, E_, 0);
        k_gemm<<<gE, blk, 0, stream>>>(Y, Wv2 + wE, nullptr, Vb, E_, E_, 0);
        k_attn2<<<gA2, blk, 0, stream>>>(Qb, Kb, Vb, Tb, sep);
        k_gemm<<<gE, blk, 0, stream>>>(Tb, Wo2 + wE, Y, Y, E_, E_, 0);
        k_rms<<<gR, blk, 0, stream>>>(Y, g2 + (size_t)i * E_, X, 1);
        // --- MLP ---
        k_gemm<<<gF, blk, 0, stream>>>(X, W1 + wF, nullptr, H1, F_, E_, 1);
        k_gemm<<<gE, blk, 0, stream>>>(H1, W2 + wF, X, Tb, E_, F_, 0);
        k_rms<<<gR, blk, 0, stream>>>(Tb, g3 + (size_t)i * E_, X, 2);
    }
}

// Round 2
// 2918.717 us; speedup vs baseline: 2.2987x; 2.2987x over previous
//
#include <hip/hip_runtime.h>
#include <math.h>

#define B_ 4
#define R_ 1024
#define G_ 8
#define E_ 192
#define H_ 6
#define D_ 32
#define L_ 4
#define F_ 384
#define M_ (B_*R_*G_)              // 32768 rows
static const size_t NBUF = (size_t)M_ * E_;   // 6291456 floats per activation buffer

typedef __attribute__((ext_vector_type(8))) short bf16x8;
typedef __attribute__((ext_vector_type(8))) unsigned short u16x8;
typedef __attribute__((ext_vector_type(4))) float f32x4;

__device__ __forceinline__ float gelu_exact(float x) {
    return 0.5f * x * (1.0f + erff(x * 0.7071067811865475f));
}

__device__ __forceinline__ unsigned short f2bf(float f) {
    union { float f; unsigned u; } v; v.f = f;
    unsigned r = v.u + 0x7fffu + ((v.u >> 16) & 1u);   // RNE
    return (unsigned short)(r >> 16);
}

// C[M,N] = act(A[M,K] @ W[K,N]) + Cres   (Cres may be null; act: 0 none, 1 exact-GELU)
__global__ __launch_bounds__(256)
void k_gemm(const float* __restrict__ A, const float* __restrict__ W,
            const float* __restrict__ Cres, float* __restrict__ C,
            int N, int K, int act)
{
    __shared__ float As[16][65];
    __shared__ float Bs[16][65];
    const int m0 = blockIdx.x * 64;
    const int n0 = blockIdx.y * 64;
    const int tid = threadIdx.x;
    const int tx = tid & 15, ty = tid >> 4;
    const int arow = tid >> 2, ac4 = (tid & 3) << 2;
    const int brow = tid >> 4, bc4 = (tid & 15) << 2;
    float acc[4][4] = {};
    for (int k0 = 0; k0 < K; k0 += 16) {
        float4 a4 = *(const float4*)(A + (size_t)(m0 + arow) * K + (k0 + ac4));
        float4 b4 = *(const float4*)(W + (size_t)(k0 + brow) * N + (n0 + bc4));
        As[ac4 + 0][arow] = a4.x; As[ac4 + 1][arow] = a4.y;
        As[ac4 + 2][arow] = a4.z; As[ac4 + 3][arow] = a4.w;
        Bs[brow][bc4 + 0] = b4.x; Bs[brow][bc4 + 1] = b4.y;
        Bs[brow][bc4 + 2] = b4.z; Bs[brow][bc4 + 3] = b4.w;
        __syncthreads();
#pragma unroll
        for (int kk = 0; kk < 16; ++kk) {
            float a[4], b[4];
#pragma unroll
            for (int i = 0; i < 4; ++i) a[i] = As[kk][ty * 4 + i];
#pragma unroll
            for (int j = 0; j < 4; ++j) b[j] = Bs[kk][tx * 4 + j];
#pragma unroll
            for (int i = 0; i < 4; ++i)
#pragma unroll
                for (int j = 0; j < 4; ++j)
                    acc[i][j] += a[i] * b[j];
        }
        __syncthreads();
    }
#pragma unroll
    for (int i = 0; i < 4; ++i) {
        const int m = m0 + ty * 4 + i;
        const size_t off = (size_t)m * N + (n0 + tx * 4);
        float v0 = acc[i][0], v1 = acc[i][1], v2 = acc[i][2], v3 = acc[i][3];
        if (act) { v0 = gelu_exact(v0); v1 = gelu_exact(v1);
                   v2 = gelu_exact(v2); v3 = gelu_exact(v3); }
        if (Cres) {
            float4 r4 = *(const float4*)(Cres + off);
            v0 += r4.x; v1 += r4.y; v2 += r4.z; v3 += r4.w;
        }
        float4 o4; o4.x = v0; o4.y = v1; o4.z = v2; o4.w = v3;
        *(float4*)(C + off) = o4;
    }
}

// Feature-group attention: 4096 seqs of length G=8, H=6 heads, D=32.
__global__ __launch_bounds__(256)
void k_attn1(const float* __restrict__ Q, const float* __restrict__ K,
             const float* __restrict__ V, float* __restrict__ T)
{
    const int wave = blockIdx.x * 4 + (threadIdx.x >> 6);
    const int lane = threadIdx.x & 63;
    const int seq = wave / H_;
    const int h = wave % H_;
    const int i = lane >> 3, j = lane & 7;
    const float4* qp = (const float4*)(Q + ((size_t)(seq * G_ + i)) * E_ + h * D_);
    const float4* kp = (const float4*)(K + ((size_t)(seq * G_ + j)) * E_ + h * D_);
    float s = 0.f;
#pragma unroll
    for (int d4 = 0; d4 < 8; ++d4) {
        float4 qv = qp[d4], kv = kp[d4];
        s += qv.x * kv.x + qv.y * kv.y + qv.z * kv.z + qv.w * kv.w;
    }
    s *= 0.17677669529663687f;  // 1/sqrt(32)
    float mx = s;
#pragma unroll
    for (int off = 1; off < 8; off <<= 1) mx = fmaxf(mx, __shfl_xor(mx, off));
    float p = __expf(s - mx);
    float sum = p;
#pragma unroll
    for (int off = 1; off < 8; off <<= 1) sum += __shfl_xor(sum, off);
    p /= sum;
    const int base = lane & ~7;
    float o0 = 0.f, o1 = 0.f, o2 = 0.f, o3 = 0.f;
#pragma unroll
    for (int jj = 0; jj < 8; ++jj) {
        float pj = __shfl(p, base + jj);
        const float4 vv = *(const float4*)(V + ((size_t)(seq * G_ + jj)) * E_ + h * D_ + j * 4);
        o0 += pj * vv.x; o1 += pj * vv.y; o2 += pj * vv.z; o3 += pj * vv.w;
    }
    float4 ov; ov.x = o0; ov.y = o1; ov.z = o2; ov.w = o3;
    *(float4*)(T + ((size_t)(seq * G_ + i)) * E_ + h * D_ + j * 4) = ov;
}

// Row attention, MFMA flash version.
// Grid: 192 (s,h) * 16 q-tiles of 64 rows. Block 256 = 4 waves, 16 q-rows/wave.
// Keys [0,sep) staged per 64-chunk into LDS (bf16); swapped QK^T (S^T = K*Q^T),
// online softmax in-register, P via per-wave LDS, O^T accumulated in f32.
__global__ __launch_bounds__(256)
void k_attn2(const float* __restrict__ Qg, const float* __restrict__ Kg,
             const float* __restrict__ Vg, float* __restrict__ T,
             const int* __restrict__ sep_ptr)
{
    __shared__ unsigned short K_lds[64][40];    // key-major, rows padded to 80B
    __shared__ unsigned short Vt_lds[32][72];   // d-major (V^T), rows padded to 144B
    __shared__ unsigned short P_lds[4][16][72]; // per-wave P[q][key], padded

    const int sep = *sep_ptr;
    const int bid = blockIdx.x;
    const int sh = bid >> 4;                    // 0..191
    const int qtile = bid & 15;
    const int s = sh / H_, h = sh % H_;
    const int q0 = qtile * 64;

    const int tid = threadIdx.x;
    const int w = tid >> 6;
    const int lane = tid & 63;
    const int l15 = lane & 15;
    const int g = lane >> 4;                    // 0..3

    // hoisted Q fragment (query head is always h), pre-scaled by 1/sqrt(D)
    const int qrow = q0 + w * 16 + l15;
    u16x8 qf;
    {
        const float* qp = Qg + ((size_t)s * R_ + qrow) * E_ + h * D_ + g * 8;
        float4 x = *(const float4*)qp;
        float4 y = *(const float4*)(qp + 4);
        const float sc = 0.17677669529663687f;
        qf[0] = f2bf(x.x * sc); qf[1] = f2bf(x.y * sc);
        qf[2] = f2bf(x.z * sc); qf[3] = f2bf(x.w * sc);
        qf[4] = f2bf(y.x * sc); qf[5] = f2bf(y.y * sc);
        qf[6] = f2bf(y.z * sc); qf[7] = f2bf(y.w * sc);
    }

    const bool lo = (q0 < sep);
    const bool hi = (q0 + 64 > sep);
    const int npass = (lo && hi) ? 2 : 1;
    const int nChunk = (sep + 63) >> 6;

    const int skey = tid >> 2;                  // staging: key 0..63
    const int sg   = tid & 3;                   // staging: 8-col group

    for (int pass = 0; pass < npass; ++pass) {
        const int hk = (pass == 0) ? (lo ? h : 0) : 0;
        const float* Kb = Kg + (size_t)s * R_ * E_ + hk * D_;
        const float* Vb = Vg + (size_t)s * R_ * E_ + hk * D_;

        float mrun = -1e30f, lrun = 0.f;
        f32x4 o0 = {0.f, 0.f, 0.f, 0.f};
        f32x4 o1 = {0.f, 0.f, 0.f, 0.f};

        for (int kc = 0; kc < nChunk; ++kc) {
            const int kbase = kc * 64;
            __syncthreads();
            // ---- stage K chunk (bf16, key-major) ----
            {
                const float* src = Kb + (size_t)(kbase + skey) * E_ + sg * 8;
                float4 x = *(const float4*)src;
                float4 y = *(const float4*)(src + 4);
                u16x8 kv;
                kv[0] = f2bf(x.x); kv[1] = f2bf(x.y); kv[2] = f2bf(x.z); kv[3] = f2bf(x.w);
                kv[4] = f2bf(y.x); kv[5] = f2bf(y.y); kv[6] = f2bf(y.z); kv[7] = f2bf(y.w);
                *(u16x8*)&K_lds[skey][sg * 8] = kv;
            }
            // ---- stage V chunk transposed (bf16, d-major) ----
            {
                const int d0 = sg * 8;
                const float* src = Vb + (size_t)(kbase + skey) * E_ + d0;
                float4 x = *(const float4*)src;
                float4 y = *(const float4*)(src + 4);
                Vt_lds[d0 + 0][skey] = f2bf(x.x);
                Vt_lds[d0 + 1][skey] = f2bf(x.y);
                Vt_lds[d0 + 2][skey] = f2bf(x.z);
                Vt_lds[d0 + 3][skey] = f2bf(x.w);
                Vt_lds[d0 + 4][skey] = f2bf(y.x);
                Vt_lds[d0 + 5][skey] = f2bf(y.y);
                Vt_lds[d0 + 6][skey] = f2bf(y.z);
                Vt_lds[d0 + 7][skey] = f2bf(y.w);
            }
            __syncthreads();

            // ---- S^T = K * Q^T : 4 key-tiles of 16 ----
            f32x4 sc[4];
            const f32x4 zf = {0.f, 0.f, 0.f, 0.f};
#pragma unroll
            for (int t = 0; t < 4; ++t) {
                bf16x8 a = *(const bf16x8*)&K_lds[t * 16 + l15][g * 8];
                sc[t] = __builtin_amdgcn_mfma_f32_16x16x32_bf16(a, (bf16x8)qf, zf, 0, 0, 0);
            }
            // ---- mask + row max (lane holds 16 scores of q-row l15) ----
            float mx = -1e30f;
#pragma unroll
            for (int t = 0; t < 4; ++t)
#pragma unroll
                for (int r = 0; r < 4; ++r) {
                    const int key = kbase + t * 16 + g * 4 + r;
                    float sv = (key < sep) ? sc[t][r] : -1e30f;
                    sc[t][r] = sv;
                    mx = fmaxf(mx, sv);
                }
            mx = fmaxf(mx, __shfl_xor(mx, 16));
            mx = fmaxf(mx, __shfl_xor(mx, 32));
            const float mnew = fmaxf(mrun, mx);
            const float scale = __expf(mrun - mnew);
            // ---- P = exp(S - m), store to per-wave LDS ----
            float psum = 0.f;
#pragma unroll
            for (int t = 0; t < 4; ++t) {
                ushort4 pw;
#pragma unroll
                for (int r = 0; r < 4; ++r) {
                    const int key = kbase + t * 16 + g * 4 + r;
                    const float p = (key < sep) ? __expf(sc[t][r] - mnew) : 0.f;
                    psum += p;
                    ((unsigned short*)&pw)[r] = f2bf(p);
                }
                *(ushort4*)&P_lds[w][l15][t * 16 + g * 4] = pw;
            }
            psum += __shfl_xor(psum, 16);
            psum += __shfl_xor(psum, 32);
            lrun = lrun * scale + psum;
#pragma unroll
            for (int r = 0; r < 4; ++r) { o0[r] *= scale; o1[r] *= scale; }
            // ---- O^T += V^T * P^T ----
#pragma unroll
            for (int ks = 0; ks < 2; ++ks) {
                bf16x8 pb = *(const bf16x8*)&P_lds[w][l15][ks * 32 + g * 8];
                bf16x8 va0 = *(const bf16x8*)&Vt_lds[l15][ks * 32 + g * 8];
                bf16x8 va1 = *(const bf16x8*)&Vt_lds[16 + l15][ks * 32 + g * 8];
                o0 = __builtin_amdgcn_mfma_f32_16x16x32_bf16(va0, pb, o0, 0, 0, 0);
                o1 = __builtin_amdgcn_mfma_f32_16x16x32_bf16(va1, pb, o1, 0, 0, 0);
            }
            mrun = mnew;
        }

        // ---- epilogue: O = O^T / l ----
        const bool valid = (npass == 1) || (pass == 0 ? (qrow < sep) : (qrow >= sep));
        if (valid) {
            const float inv = 1.f / lrun;
            float* tp = T + ((size_t)s * R_ + qrow) * E_ + h * D_;
            float4 v0; v0.x = o0[0] * inv; v0.y = o0[1] * inv; v0.z = o0[2] * inv; v0.w = o0[3] * inv;
            float4 v1; v1.x = o1[0] * inv; v1.y = o1[1] * inv; v1.z = o1[2] * inv; v1.w = o1[3] * inv;
            *(float4*)(tp + g * 4)      = v0;
            *(float4*)(tp + 16 + g * 4) = v1;
        }
    }
}

// RMSNorm over last dim (192) with optional layout transpose.
__global__ __launch_bounds__(256)
void k_rms(const float* __restrict__ In, const float* __restrict__ g,
           float* __restrict__ Out, int mode)
{
    const int row = blockIdx.x * 4 + (threadIdx.x >> 6);
    const int lane = threadIdx.x & 63;
    const float* ip = In + (size_t)row * E_;
    float v0 = ip[lane], v1 = ip[lane + 64], v2 = ip[lane + 128];
    float ss = v0 * v0 + v1 * v1 + v2 * v2;
#pragma unroll
    for (int off = 32; off > 0; off >>= 1) ss += __shfl_xor(ss, off);
    const float inv = rsqrtf(ss * (1.0f / 192.0f) + 1.1920929e-07f);
    size_t orow;
    if (mode == 0) {
        const int b = row / (R_ * G_);
        const int r = (row / G_) % R_;
        const int gg = row % G_;
        orow = ((size_t)(b * G_ + gg)) * R_ + r;
    } else if (mode == 1) {
        const int b = row / (G_ * R_);
        const int gg = (row / R_) % G_;
        const int r = row % R_;
        orow = ((size_t)(b * R_ + r)) * G_ + gg;
    } else {
        orow = row;
    }
    float* op = Out + orow * E_;
    op[lane]       = v0 * inv * g[lane];
    op[lane + 64]  = v1 * inv * g[lane + 64];
    op[lane + 128] = v2 * inv * g[lane + 128];
}

extern "C" void kernel_launch(void* const* d_in, const int* in_sizes, int n_in,
                              void* d_out, int out_size, void* d_ws, size_t ws_size,
                              hipStream_t stream) {
    const float* hidden = (const float*)d_in[0];
    const float* Wq1 = (const float*)d_in[1];
    const float* Wk1 = (const float*)d_in[2];
    const float* Wv1 = (const float*)d_in[3];
    const float* Wo1 = (const float*)d_in[4];
    const float* Wq2 = (const float*)d_in[5];
    const float* Wk2 = (const float*)d_in[6];
    const float* Wv2 = (const float*)d_in[7];
    const float* Wo2 = (const float*)d_in[8];
    const float* W1  = (const float*)d_in[9];
    const float* W2  = (const float*)d_in[10];
    const float* g1  = (const float*)d_in[11];
    const float* g2  = (const float*)d_in[12];
    const float* g3  = (const float*)d_in[13];
    const int*   sep = (const int*)d_in[14];

    float* X  = (float*)d_out;
    float* ws = (float*)d_ws;
    float* Y  = ws;
    float* Qb = ws + NBUF;
    float* Kb = ws + 2 * NBUF;
    float* Vb = ws + 3 * NBUF;
    float* Tb = ws + 4 * NBUF;
    float* H1 = Qb;

    const dim3 blk(256);
    const dim3 gE(M_ / 64, E_ / 64);
    const dim3 gF(M_ / 64, F_ / 64);
    const dim3 gA1((4096 * H_) / 4);
    const dim3 gA2(32 * H_ * 16);       // (s,h) x 16 q-tiles of 64 rows
    const dim3 gR(M_ / 4);

    for (int i = 0; i < L_; ++i) {
        const float* Xin = (i == 0) ? hidden : X;
        const size_t wE = (size_t)i * E_ * E_;
        const size_t wF = (size_t)i * E_ * F_;
        // --- feature-group attention ---
        k_gemm<<<gE, blk, 0, stream>>>(Xin, Wq1 + wE, nullptr, Qb, E_, E_, 0);
        k_gemm<<<gE, blk, 0, stream>>>(Xin, Wk1 + wE, nullptr, Kb, E_, E_, 0);
        k_gemm<<<gE, blk, 0, stream>>>(Xin, Wv1 + wE, nullptr, Vb, E_, E_, 0);
        k_attn1<<<gA1, blk, 0, stream>>>(Qb, Kb, Vb, Tb);
        k_gemm<<<gE, blk, 0, stream>>>(Tb, Wo1 + wE, Xin, X, E_, E_, 0);
        k_rms<<<gR, blk, 0, stream>>>(X, g1 + (size_t)i * E_, Y, 0);
        // --- row attention ---
        k_gemm<<<gE, blk, 0, stream>>>(Y, Wq2 + wE, nullptr, Qb, E_, E_, 0);
        k_gemm<<<gE, blk, 0, stream>>>(Y, Wk2 + wE, nullptr, Kb, E_, E_, 0);
        k_gemm<<<gE, blk, 0, stream>>>(Y, Wv2 + wE, nullptr, Vb, E_, E_, 0);
        k_attn2<<<gA2, blk, 0, stream>>>(Qb, Kb, Vb, Tb, sep);
        k_gemm<<<gE, blk, 0, stream>>>(Tb, Wo2 + wE, Y, Y, E_, E_, 0);
        k_rms<<<gR, blk, 0, stream>>>(Y, g2 + (size_t)i * E_, X, 1);
        // --- MLP ---
        k_gemm<<<gF, blk, 0, stream>>>(X, W1 + wF, nullptr, H1, F_, E_, 1);
        k_gemm<<<gE, blk, 0, stream>>>(H1, W2 + wF, X, Tb, E_, F_, 0);
        k_rms<<<gR, blk, 0, stream>>>(Tb, g3 + (size_t)i * E_, X, 2);
    }
}

// Round 3
// 966.635 us; speedup vs baseline: 6.9409x; 3.0195x over previous
//
#include <hip/hip_runtime.h>
#include <math.h>

#define B_ 4
#define R_ 1024
#define G_ 8
#define E_ 192
#define H_ 6
#define D_ 32
#define L_ 4
#define F_ 384
#define M_ (B_*R_*G_)              // 32768 rows
static const size_t NBUF = (size_t)M_ * E_;       // 6291456 elems per activation buffer
static const size_t WPL  = 8 * (size_t)E_ * E_ + 2 * (size_t)E_ * F_;  // 442368 bf16/layer

typedef __attribute__((ext_vector_type(8))) short bf16x8;
typedef __attribute__((ext_vector_type(8))) unsigned short u16x8;
typedef __attribute__((ext_vector_type(4))) float f32x4;

__device__ __forceinline__ float gelu_exact(float x) {
    return 0.5f * x * (1.0f + erff(x * 0.7071067811865475f));
}
__device__ __forceinline__ unsigned short f2bf(float f) {
    union { float f; unsigned u; } v; v.f = f;
    unsigned r = v.u + 0x7fffu + ((v.u >> 16) & 1u);   // RNE
    return (unsigned short)(r >> 16);
}
__device__ __forceinline__ float bf2f(unsigned short h) {
    union { unsigned u; float f; } v; v.u = ((unsigned)h) << 16; return v.f;
}

// ---- one-shot: transpose+convert all weights to Wt[N][K] bf16 (scale folded into Wq1/Wq2)
__global__ __launch_bounds__(256)
void k_convw_all(const float* __restrict__ Wq1, const float* __restrict__ Wk1,
                 const float* __restrict__ Wv1, const float* __restrict__ Wo1,
                 const float* __restrict__ Wq2, const float* __restrict__ Wk2,
                 const float* __restrict__ Wv2, const float* __restrict__ Wo2,
                 const float* __restrict__ W1,  const float* __restrict__ W2,
                 unsigned short* __restrict__ Wt)
{
    const int t = blockIdx.x;
    const int layer = t / 432;
    const int r = t % 432;
    const float* src; unsigned short* dst; int K, N; float scale = 1.f; int tile;
    if (r < 288) {
        const int w = r / 36; tile = r % 36; K = E_; N = E_;
        const float* tab[8] = {Wq1, Wk1, Wv1, Wo1, Wq2, Wk2, Wv2, Wo2};
        src = tab[w] + (size_t)layer * E_ * E_;
        dst = Wt + (size_t)layer * WPL + (size_t)w * E_ * E_;
        if (w == 0 || w == 4) scale = 0.17677669529663687f;   // 1/sqrt(32)
    } else if (r < 360) {
        tile = r - 288; K = E_; N = F_;
        src = W1 + (size_t)layer * E_ * F_;
        dst = Wt + (size_t)layer * WPL + 8 * (size_t)E_ * E_;
    } else {
        tile = r - 360; K = F_; N = E_;
        src = W2 + (size_t)layer * E_ * F_;
        dst = Wt + (size_t)layer * WPL + 8 * (size_t)E_ * E_ + (size_t)E_ * F_;
    }
    const int ntx = N / 32;
    const int kb = (tile / ntx) * 32, nb = (tile % ntx) * 32;
    __shared__ float tl[32][33];
    const int tx = threadIdx.x & 31, ty = threadIdx.x >> 5;
    for (int i2 = 0; i2 < 32; i2 += 8)
        tl[ty + i2][tx] = src[(size_t)(kb + ty + i2) * N + nb + tx];
    __syncthreads();
    for (int i2 = 0; i2 < 32; i2 += 8)
        dst[(size_t)(nb + ty + i2) * K + kb + tx] = f2bf(tl[tx][ty + i2] * scale);
}

// ---- MFMA GEMM: C[M,N] = act(A[M,K] @ Wt^T) (+res). Tile 64x192, BK=32, 4 waves.
template<bool ABF16, bool OUTBF16, bool RES, int ACT>
__global__ __launch_bounds__(256)
void k_gemm_mfma(const void* __restrict__ Ap, const unsigned short* __restrict__ Wt,
                 const float* __restrict__ Cres, void* __restrict__ Cp,
                 int N, int K)
{
    __shared__ unsigned short As[64][40];     // rows padded to 80B -> 2-way (free)
    __shared__ unsigned short Bs[192][40];
    const int m0 = blockIdx.x * 64;
    const int n0 = blockIdx.y * 192;
    const int tid = threadIdx.x;
    const int w = tid >> 6, lane = tid & 63, l15 = lane & 15, g = lane >> 4;
    const int arow = tid >> 2, akoff = (tid & 3) << 3;
    f32x4 acc[4][3];
#pragma unroll
    for (int mt = 0; mt < 4; ++mt)
#pragma unroll
        for (int nt = 0; nt < 3; ++nt)
#pragma unroll
            for (int r2 = 0; r2 < 4; ++r2) acc[mt][nt][r2] = 0.f;
    const int nK = K >> 5;
    for (int kc = 0; kc < nK; ++kc) {
        const int k0 = kc << 5;
        // stage A (convert f32->bf16 if needed)
        u16x8 av;
        if (ABF16) {
            av = *(const u16x8*)((const unsigned short*)Ap + (size_t)(m0 + arow) * K + k0 + akoff);
        } else {
            const float* ap = (const float*)Ap + (size_t)(m0 + arow) * K + k0 + akoff;
            float4 x = *(const float4*)ap, y = *(const float4*)(ap + 4);
            av[0] = f2bf(x.x); av[1] = f2bf(x.y); av[2] = f2bf(x.z); av[3] = f2bf(x.w);
            av[4] = f2bf(y.x); av[5] = f2bf(y.y); av[6] = f2bf(y.z); av[7] = f2bf(y.w);
        }
        *(u16x8*)&As[arow][akoff] = av;
        // stage B (already bf16 [N][K])
#pragma unroll
        for (int j = 0; j < 3; ++j) {
            const int v = tid + 256 * j;
            const int bn = v >> 2, bk = (v & 3) << 3;
            u16x8 bv = *(const u16x8*)(Wt + (size_t)(n0 + bn) * K + k0 + bk);
            *(u16x8*)&Bs[bn][bk] = bv;
        }
        __syncthreads();
        bf16x8 af[4], bfr[3];
#pragma unroll
        for (int mt = 0; mt < 4; ++mt) af[mt] = *(const bf16x8*)&As[mt * 16 + l15][g * 8];
#pragma unroll
        for (int nt = 0; nt < 3; ++nt) bfr[nt] = *(const bf16x8*)&Bs[w * 48 + nt * 16 + l15][g * 8];
#pragma unroll
        for (int mt = 0; mt < 4; ++mt)
#pragma unroll
            for (int nt = 0; nt < 3; ++nt)
                acc[mt][nt] = __builtin_amdgcn_mfma_f32_16x16x32_bf16(af[mt], bfr[nt], acc[mt][nt], 0, 0, 0);
        __syncthreads();
    }
#pragma unroll
    for (int mt = 0; mt < 4; ++mt) {
#pragma unroll
        for (int r2 = 0; r2 < 4; ++r2) {
            const int m = m0 + mt * 16 + g * 4 + r2;
#pragma unroll
            for (int nt = 0; nt < 3; ++nt) {
                const int n = n0 + w * 48 + nt * 16 + l15;
                float v = acc[mt][nt][r2];
                if (ACT) v = gelu_exact(v);
                if (RES) v += Cres[(size_t)m * N + n];
                if (OUTBF16) ((unsigned short*)Cp)[(size_t)m * N + n] = f2bf(v);
                else         ((float*)Cp)[(size_t)m * N + n] = v;
            }
        }
    }
}

// ---- Feature-group attention (bf16 I/O). Q pre-scaled via Wq1 fold.
__global__ __launch_bounds__(256)
void k_attn1(const unsigned short* __restrict__ Q, const unsigned short* __restrict__ K,
             const unsigned short* __restrict__ V, unsigned short* __restrict__ T)
{
    const int wave = blockIdx.x * 4 + (threadIdx.x >> 6);
    const int lane = threadIdx.x & 63;
    const int seq = wave / H_;
    const int h = wave % H_;
    const int i = lane >> 3, j = lane & 7;
    const unsigned short* qp = Q + ((size_t)(seq * G_ + i)) * E_ + h * D_;
    const unsigned short* kp = K + ((size_t)(seq * G_ + j)) * E_ + h * D_;
    float s = 0.f;
#pragma unroll
    for (int d8 = 0; d8 < 4; ++d8) {
        u16x8 qv = *(const u16x8*)(qp + d8 * 8);
        u16x8 kv = *(const u16x8*)(kp + d8 * 8);
#pragma unroll
        for (int e = 0; e < 8; ++e) s += bf2f(qv[e]) * bf2f(kv[e]);
    }
    float mx = s;
#pragma unroll
    for (int off = 1; off < 8; off <<= 1) mx = fmaxf(mx, __shfl_xor(mx, off));
    float p = __expf(s - mx);
    float sum = p;
#pragma unroll
    for (int off = 1; off < 8; off <<= 1) sum += __shfl_xor(sum, off);
    p /= sum;
    const int base = lane & ~7;
    float o0 = 0.f, o1 = 0.f, o2 = 0.f, o3 = 0.f;
#pragma unroll
    for (int jj = 0; jj < 8; ++jj) {
        float pj = __shfl(p, base + jj);
        ushort4 vv = *(const ushort4*)(V + ((size_t)(seq * G_ + jj)) * E_ + h * D_ + j * 4);
        o0 += pj * bf2f(vv.x); o1 += pj * bf2f(vv.y);
        o2 += pj * bf2f(vv.z); o3 += pj * bf2f(vv.w);
    }
    ushort4 ov; ov.x = f2bf(o0); ov.y = f2bf(o1); ov.z = f2bf(o2); ov.w = f2bf(o3);
    *(ushort4*)(T + ((size_t)(seq * G_ + i)) * E_ + h * D_ + j * 4) = ov;
}

// ---- Row attention, MFMA flash, bf16 I/O (Q pre-scaled via Wq2 fold).
__global__ __launch_bounds__(256)
void k_attn2(const unsigned short* __restrict__ Qg, const unsigned short* __restrict__ Kg,
             const unsigned short* __restrict__ Vg, unsigned short* __restrict__ T,
             const int* __restrict__ sep_ptr)
{
    __shared__ unsigned short K_lds[64][40];
    __shared__ unsigned short Vt_lds[32][72];
    __shared__ unsigned short P_lds[4][16][72];

    const int sep = *sep_ptr;
    const int bid = blockIdx.x;
    const int sh = bid >> 4;
    const int qtile = bid & 15;
    const int s = sh / H_, h = sh % H_;
    const int q0 = qtile * 64;

    const int tid = threadIdx.x;
    const int w = tid >> 6;
    const int lane = tid & 63;
    const int l15 = lane & 15;
    const int g = lane >> 4;

    const int qrow = q0 + w * 16 + l15;
    u16x8 qf = *(const u16x8*)(Qg + ((size_t)s * R_ + qrow) * E_ + h * D_ + g * 8);

    const bool lo = (q0 < sep);
    const bool hi = (q0 + 64 > sep);
    const int npass = (lo && hi) ? 2 : 1;
    const int nChunk = (sep + 63) >> 6;

    const int skey = tid >> 2;
    const int sg   = tid & 3;

    for (int pass = 0; pass < npass; ++pass) {
        const int hk = (pass == 0) ? (lo ? h : 0) : 0;
        const unsigned short* Kb = Kg + (size_t)s * R_ * E_ + hk * D_;
        const unsigned short* Vb = Vg + (size_t)s * R_ * E_ + hk * D_;

        float mrun = -1e30f, lrun = 0.f;
        f32x4 o0 = {0.f, 0.f, 0.f, 0.f};
        f32x4 o1 = {0.f, 0.f, 0.f, 0.f};

        for (int kc = 0; kc < nChunk; ++kc) {
            const int kbase = kc * 64;
            __syncthreads();
            *(u16x8*)&K_lds[skey][sg * 8] =
                *(const u16x8*)(Kb + (size_t)(kbase + skey) * E_ + sg * 8);
            {
                const int d0 = sg * 8;
                u16x8 vv = *(const u16x8*)(Vb + (size_t)(kbase + skey) * E_ + d0);
#pragma unroll
                for (int e = 0; e < 8; ++e) Vt_lds[d0 + e][skey] = vv[e];
            }
            __syncthreads();

            f32x4 sc[4];
            const f32x4 zf = {0.f, 0.f, 0.f, 0.f};
#pragma unroll
            for (int t = 0; t < 4; ++t) {
                bf16x8 a = *(const bf16x8*)&K_lds[t * 16 + l15][g * 8];
                sc[t] = __builtin_amdgcn_mfma_f32_16x16x32_bf16(a, (bf16x8)qf, zf, 0, 0, 0);
            }
            float mx = -1e30f;
#pragma unroll
            for (int t = 0; t < 4; ++t)
#pragma unroll
                for (int r = 0; r < 4; ++r) {
                    const int key = kbase + t * 16 + g * 4 + r;
                    float sv = (key < sep) ? sc[t][r] : -1e30f;
                    sc[t][r] = sv;
                    mx = fmaxf(mx, sv);
                }
            mx = fmaxf(mx, __shfl_xor(mx, 16));
            mx = fmaxf(mx, __shfl_xor(mx, 32));
            const float mnew = fmaxf(mrun, mx);
            const float scale = __expf(mrun - mnew);
            float psum = 0.f;
#pragma unroll
            for (int t = 0; t < 4; ++t) {
                ushort4 pw;
#pragma unroll
                for (int r = 0; r < 4; ++r) {
                    const int key = kbase + t * 16 + g * 4 + r;
                    const float p = (key < sep) ? __expf(sc[t][r] - mnew) : 0.f;
                    psum += p;
                    ((unsigned short*)&pw)[r] = f2bf(p);
                }
                *(ushort4*)&P_lds[w][l15][t * 16 + g * 4] = pw;
            }
            psum += __shfl_xor(psum, 16);
            psum += __shfl_xor(psum, 32);
            lrun = lrun * scale + psum;
#pragma unroll
            for (int r = 0; r < 4; ++r) { o0[r] *= scale; o1[r] *= scale; }
#pragma unroll
            for (int ks = 0; ks < 2; ++ks) {
                bf16x8 pb = *(const bf16x8*)&P_lds[w][l15][ks * 32 + g * 8];
                bf16x8 va0 = *(const bf16x8*)&Vt_lds[l15][ks * 32 + g * 8];
                bf16x8 va1 = *(const bf16x8*)&Vt_lds[16 + l15][ks * 32 + g * 8];
                o0 = __builtin_amdgcn_mfma_f32_16x16x32_bf16(va0, pb, o0, 0, 0, 0);
                o1 = __builtin_amdgcn_mfma_f32_16x16x32_bf16(va1, pb, o1, 0, 0, 0);
            }
            mrun = mnew;
        }

        const bool valid = (npass == 1) || (pass == 0 ? (qrow < sep) : (qrow >= sep));
        if (valid) {
            const float inv = 1.f / lrun;
            unsigned short* tp = T + ((size_t)s * R_ + qrow) * E_ + h * D_;
            ushort4 v0, v1;
            v0.x = f2bf(o0[0] * inv); v0.y = f2bf(o0[1] * inv);
            v0.z = f2bf(o0[2] * inv); v0.w = f2bf(o0[3] * inv);
            v1.x = f2bf(o1[0] * inv); v1.y = f2bf(o1[1] * inv);
            v1.z = f2bf(o1[2] * inv); v1.w = f2bf(o1[3] * inv);
            *(ushort4*)(tp + g * 4)      = v0;
            *(ushort4*)(tp + 16 + g * 4) = v1;
        }
    }
}

// ---- RMSNorm over last dim (192) with optional layout transpose (f32 in/out).
__global__ __launch_bounds__(256)
void k_rms(const float* __restrict__ In, const float* __restrict__ g,
           float* __restrict__ Out, int mode)
{
    const int row = blockIdx.x * 4 + (threadIdx.x >> 6);
    const int lane = threadIdx.x & 63;
    const float* ip = In + (size_t)row * E_;
    float v0 = ip[lane], v1 = ip[lane + 64], v2 = ip[lane + 128];
    float ss = v0 * v0 + v1 * v1 + v2 * v2;
#pragma unroll
    for (int off = 32; off > 0; off >>= 1) ss += __shfl_xor(ss, off);
    const float inv = rsqrtf(ss * (1.0f / 192.0f) + 1.1920929e-07f);
    size_t orow;
    if (mode == 0) {
        const int b = row / (R_ * G_);
        const int r = (row / G_) % R_;
        const int gg = row % G_;
        orow = ((size_t)(b * G_ + gg)) * R_ + r;
    } else if (mode == 1) {
        const int b = row / (G_ * R_);
        const int gg = (row / R_) % G_;
        const int r = row % R_;
        orow = ((size_t)(b * R_ + r)) * G_ + gg;
    } else {
        orow = row;
    }
    float* op = Out + orow * E_;
    op[lane]       = v0 * inv * g[lane];
    op[lane + 64]  = v1 * inv * g[lane + 64];
    op[lane + 128] = v2 * inv * g[lane + 128];
}

extern "C" void kernel_launch(void* const* d_in, const int* in_sizes, int n_in,
                              void* d_out, int out_size, void* d_ws, size_t ws_size,
                              hipStream_t stream) {
    const float* hidden = (const float*)d_in[0];
    const float* Wq1 = (const float*)d_in[1];
    const float* Wk1 = (const float*)d_in[2];
    const float* Wv1 = (const float*)d_in[3];
    const float* Wo1 = (const float*)d_in[4];
    const float* Wq2 = (const float*)d_in[5];
    const float* Wk2 = (const float*)d_in[6];
    const float* Wv2 = (const float*)d_in[7];
    const float* Wo2 = (const float*)d_in[8];
    const float* W1  = (const float*)d_in[9];
    const float* W2  = (const float*)d_in[10];
    const float* g1  = (const float*)d_in[11];
    const float* g2  = (const float*)d_in[12];
    const float* g3  = (const float*)d_in[13];
    const int*   sep = (const int*)d_in[14];

    float* X = (float*)d_out;                       // X-layout residual stream (f32)
    char* ws = (char*)d_ws;
    float*          Y  = (float*)ws;                               // 25.2 MB f32
    unsigned short* Qb = (unsigned short*)(ws + NBUF * 4);         // bf16
    unsigned short* Kb = Qb + NBUF;
    unsigned short* Vb = Kb + NBUF;
    unsigned short* Tb = Vb + NBUF;
    unsigned short* Wt = Tb + NBUF;                                // all weights, bf16 [N][K]
    unsigned short* H1 = Qb;                                       // [32768,384] bf16 aliases Qb+Kb

    const dim3 blk(256);
    const dim3 gE(M_ / 64, 1);
    const dim3 gF(M_ / 64, 2);
    const dim3 gA1((4096 * H_) / 4);
    const dim3 gA2(32 * H_ * 16);
    const dim3 gR(M_ / 4);

    // one-shot weight transpose/convert (bf16, scale folded into Wq1/Wq2)
    k_convw_all<<<dim3(432 * L_), blk, 0, stream>>>(Wq1, Wk1, Wv1, Wo1, Wq2, Wk2, Wv2, Wo2, W1, W2, Wt);

    for (int i = 0; i < L_; ++i) {
        const float* Xin = (i == 0) ? hidden : X;
        unsigned short* wl = Wt + (size_t)i * WPL;
        const unsigned short* wq1 = wl;
        const unsigned short* wk1 = wl + 1 * (size_t)E_ * E_;
        const unsigned short* wv1 = wl + 2 * (size_t)E_ * E_;
        const unsigned short* wo1 = wl + 3 * (size_t)E_ * E_;
        const unsigned short* wq2 = wl + 4 * (size_t)E_ * E_;
        const unsigned short* wk2 = wl + 5 * (size_t)E_ * E_;
        const unsigned short* wv2 = wl + 6 * (size_t)E_ * E_;
        const unsigned short* wo2 = wl + 7 * (size_t)E_ * E_;
        const unsigned short* w1  = wl + 8 * (size_t)E_ * E_;
        const unsigned short* w2  = wl + 8 * (size_t)E_ * E_ + (size_t)E_ * F_;

        // --- feature-group attention ---
        k_gemm_mfma<false, true, false, 0><<<gE, blk, 0, stream>>>(Xin, wq1, nullptr, Qb, E_, E_);
        k_gemm_mfma<false, true, false, 0><<<gE, blk, 0, stream>>>(Xin, wk1, nullptr, Kb, E_, E_);
        k_gemm_mfma<false, true, false, 0><<<gE, blk, 0, stream>>>(Xin, wv1, nullptr, Vb, E_, E_);
        k_attn1<<<gA1, blk, 0, stream>>>(Qb, Kb, Vb, Tb);
        k_gemm_mfma<true, false, true, 0><<<gE, blk, 0, stream>>>(Tb, wo1, Xin, X, E_, E_);
        k_rms<<<gR, blk, 0, stream>>>(X, g1 + (size_t)i * E_, Y, 0);
        // --- row attention ---
        k_gemm_mfma<false, true, false, 0><<<gE, blk, 0, stream>>>(Y, wq2, nullptr, Qb, E_, E_);
        k_gemm_mfma<false, true, false, 0><<<gE, blk, 0, stream>>>(Y, wk2, nullptr, Kb, E_, E_);
        k_gemm_mfma<false, true, false, 0><<<gE, blk, 0, stream>>>(Y, wv2, nullptr, Vb, E_, E_);
        k_attn2<<<gA2, blk, 0, stream>>>(Qb, Kb, Vb, Tb, sep);
        k_gemm_mfma<true, false, true, 0><<<gE, blk, 0, stream>>>(Tb, wo2, Y, Y, E_, E_);
        k_rms<<<gR, blk, 0, stream>>>(Y, g2 + (size_t)i * E_, X, 1);
        // --- MLP ---
        k_gemm_mfma<false, true, false, 1><<<gF, blk, 0, stream>>>(X, w1, nullptr, H1, F_, E_);
        k_gemm_mfma<true, false, true, 0><<<gE, blk, 0, stream>>>(H1, w2, X, Y, E_, F_);
        k_rms<<<gR, blk, 0, stream>>>(Y, g3 + (size_t)i * E_, X, 2);
    }
}

// Round 4
// 779.394 us; speedup vs baseline: 8.6084x; 1.2402x over previous
//
#include <hip/hip_runtime.h>
#include <hip/hip_bf16.h>
#include <math.h>

#define B_ 4
#define R_ 1024
#define G_ 8
#define E_ 192
#define H_ 6
#define D_ 32
#define L_ 4
#define F_ 384
#define M_ (B_*R_*G_)              // 32768 rows
static const size_t NBUF = (size_t)M_ * E_;       // 6291456 elems
static const size_t WPL  = 8 * (size_t)E_ * E_ + 2 * (size_t)E_ * F_;  // bf16/layer

typedef __attribute__((ext_vector_type(8))) short bf16x8;
typedef __attribute__((ext_vector_type(8))) unsigned short u16x8;
typedef __attribute__((ext_vector_type(4))) float f32x4;

__device__ __forceinline__ float gelu_exact(float x) {
    return 0.5f * x * (1.0f + erff(x * 0.7071067811865475f));
}
__device__ __forceinline__ unsigned short f2bf(float f) {
    __hip_bfloat16 h = __float2bfloat16(f);
    return *(unsigned short*)&h;
}
__device__ __forceinline__ float bf2f(unsigned short h) {
    union { unsigned u; float f; } v; v.u = ((unsigned)h) << 16; return v.f;
}

// ---- one-shot: transpose+convert all weights to Wt[N][K] bf16.
// Scale folds: Wq1 *= 1/sqrt(D); Wq2 *= log2(e)/sqrt(D)  (attn2 runs in exp2 domain).
__global__ __launch_bounds__(256)
void k_convw_all(const float* __restrict__ Wq1, const float* __restrict__ Wk1,
                 const float* __restrict__ Wv1, const float* __restrict__ Wo1,
                 const float* __restrict__ Wq2, const float* __restrict__ Wk2,
                 const float* __restrict__ Wv2, const float* __restrict__ Wo2,
                 const float* __restrict__ W1,  const float* __restrict__ W2,
                 unsigned short* __restrict__ Wt)
{
    const int t = blockIdx.x;
    const int layer = t / 432;
    const int r = t % 432;
    const float* src; unsigned short* dst; int K, N; float scale = 1.f; int tile;
    if (r < 288) {
        const int w = r / 36; tile = r % 36; K = E_; N = E_;
        const float* tab[8] = {Wq1, Wk1, Wv1, Wo1, Wq2, Wk2, Wv2, Wo2};
        src = tab[w] + (size_t)layer * E_ * E_;
        dst = Wt + (size_t)layer * WPL + (size_t)w * E_ * E_;
        if (w == 0) scale = 0.17677669529663687f;                       // 1/sqrt(32)
        if (w == 4) scale = 0.17677669529663687f * 1.4426950408889634f; // log2e/sqrt(32)
    } else if (r < 360) {
        tile = r - 288; K = E_; N = F_;
        src = W1 + (size_t)layer * E_ * F_;
        dst = Wt + (size_t)layer * WPL + 8 * (size_t)E_ * E_;
    } else {
        tile = r - 360; K = F_; N = E_;
        src = W2 + (size_t)layer * E_ * F_;
        dst = Wt + (size_t)layer * WPL + 8 * (size_t)E_ * E_ + (size_t)E_ * F_;
    }
    const int ntx = N / 32;
    const int kb = (tile / ntx) * 32, nb = (tile % ntx) * 32;
    __shared__ float tl[32][33];
    const int tx = threadIdx.x & 31, ty = threadIdx.x >> 5;
    for (int i2 = 0; i2 < 32; i2 += 8)
        tl[ty + i2][tx] = src[(size_t)(kb + ty + i2) * N + nb + tx];
    __syncthreads();
    for (int i2 = 0; i2 < 32; i2 += 8)
        dst[(size_t)(nb + ty + i2) * K + kb + tx] = f2bf(tl[tx][ty + i2] * scale);
}

// ---- MFMA GEMM, tile 64 x 192, BK=32, 4 waves.
// EPI: 0 = store bf16 at [m][n0+n], ldc
//      1 = gelu -> bf16, ldc
//      2 = +res, row-RMS*g -> bf16, transpose X->XR    (grid.y must be 1)
//      3 = +res, row-RMS*g -> bf16, transpose XR->X
//      4 = +res, row-RMS*g -> f32, no transpose
//      5 = +res, row-RMS*g -> bf16, no transpose
template<bool ABF16, bool RESBF16, int EPI>
__global__ __launch_bounds__(256)
void k_gemm_mfma(const void* __restrict__ Ap, const unsigned short* __restrict__ Wt,
                 const void* __restrict__ Resp, const float* __restrict__ gvec,
                 void* __restrict__ Cp, int ldc, int K)
{
    __shared__ unsigned short As[64][40];
    __shared__ unsigned short Bs[192][40];
    __shared__ float ss_red[4][64];
    const int m0 = blockIdx.x * 64;
    const int n0 = blockIdx.y * 192;
    const int tid = threadIdx.x;
    const int w = tid >> 6, lane = tid & 63, l15 = lane & 15, g = lane >> 4;
    const int arow = tid >> 2, akoff = (tid & 3) << 3;
    f32x4 acc[4][3];
#pragma unroll
    for (int mt = 0; mt < 4; ++mt)
#pragma unroll
        for (int nt = 0; nt < 3; ++nt)
#pragma unroll
            for (int r2 = 0; r2 < 4; ++r2) acc[mt][nt][r2] = 0.f;
    const int nK = K >> 5;
    for (int kc = 0; kc < nK; ++kc) {
        const int k0 = kc << 5;
        u16x8 av;
        if (ABF16) {
            av = *(const u16x8*)((const unsigned short*)Ap + (size_t)(m0 + arow) * K + k0 + akoff);
        } else {
            const float* ap = (const float*)Ap + (size_t)(m0 + arow) * K + k0 + akoff;
            float4 x = *(const float4*)ap, y = *(const float4*)(ap + 4);
            av[0] = f2bf(x.x); av[1] = f2bf(x.y); av[2] = f2bf(x.z); av[3] = f2bf(x.w);
            av[4] = f2bf(y.x); av[5] = f2bf(y.y); av[6] = f2bf(y.z); av[7] = f2bf(y.w);
        }
        *(u16x8*)&As[arow][akoff] = av;
#pragma unroll
        for (int j = 0; j < 3; ++j) {
            const int v = tid + 256 * j;
            const int bn = v >> 2, bk = (v & 3) << 3;
            u16x8 bv = *(const u16x8*)(Wt + (size_t)(n0 + bn) * K + k0 + bk);
            *(u16x8*)&Bs[bn][bk] = bv;
        }
        __syncthreads();
        bf16x8 af[4], bfr[3];
#pragma unroll
        for (int mt = 0; mt < 4; ++mt) af[mt] = *(const bf16x8*)&As[mt * 16 + l15][g * 8];
#pragma unroll
        for (int nt = 0; nt < 3; ++nt) bfr[nt] = *(const bf16x8*)&Bs[w * 48 + nt * 16 + l15][g * 8];
#pragma unroll
        for (int mt = 0; mt < 4; ++mt)
#pragma unroll
            for (int nt = 0; nt < 3; ++nt)
                acc[mt][nt] = __builtin_amdgcn_mfma_f32_16x16x32_bf16(af[mt], bfr[nt], acc[mt][nt], 0, 0, 0);
        __syncthreads();
    }

    if (EPI <= 1) {
#pragma unroll
        for (int mt = 0; mt < 4; ++mt)
#pragma unroll
            for (int r2 = 0; r2 < 4; ++r2) {
                const int m = m0 + mt * 16 + g * 4 + r2;
#pragma unroll
                for (int nt = 0; nt < 3; ++nt) {
                    const int n = w * 48 + nt * 16 + l15;
                    float v = acc[mt][nt][r2];
                    if (EPI == 1) v = gelu_exact(v);
                    ((unsigned short*)Cp)[(size_t)m * ldc + n0 + n] = f2bf(v);
                }
            }
        return;
    }

    // --- residual + row RMSNorm epilogue (grid.y == 1, N == 192) ---
    float ssp[4][4];
#pragma unroll
    for (int mt = 0; mt < 4; ++mt)
#pragma unroll
        for (int r2 = 0; r2 < 4; ++r2) ssp[mt][r2] = 0.f;
#pragma unroll
    for (int mt = 0; mt < 4; ++mt)
#pragma unroll
        for (int r2 = 0; r2 < 4; ++r2) {
            const int m = m0 + mt * 16 + g * 4 + r2;
#pragma unroll
            for (int nt = 0; nt < 3; ++nt) {
                const int n = w * 48 + nt * 16 + l15;
                float rres = RESBF16 ? bf2f(((const unsigned short*)Resp)[(size_t)m * E_ + n])
                                     : ((const float*)Resp)[(size_t)m * E_ + n];
                float v = acc[mt][nt][r2] + rres;
                acc[mt][nt][r2] = v;
                ssp[mt][r2] += v * v;
            }
        }
#pragma unroll
    for (int off = 1; off < 16; off <<= 1)
#pragma unroll
        for (int mt = 0; mt < 4; ++mt)
#pragma unroll
            for (int r2 = 0; r2 < 4; ++r2)
                ssp[mt][r2] += __shfl_xor(ssp[mt][r2], off);
    if (l15 == 0) {
#pragma unroll
        for (int mt = 0; mt < 4; ++mt)
#pragma unroll
            for (int r2 = 0; r2 < 4; ++r2)
                ss_red[w][mt * 16 + g * 4 + r2] = ssp[mt][r2];
    }
    __syncthreads();
#pragma unroll
    for (int mt = 0; mt < 4; ++mt) {
#pragma unroll
        for (int r2 = 0; r2 < 4; ++r2) {
            const int lrow = mt * 16 + g * 4 + r2;
            const float ss = ss_red[0][lrow] + ss_red[1][lrow] + ss_red[2][lrow] + ss_red[3][lrow];
            const float inv = rsqrtf(ss * (1.0f / 192.0f) + 1.1920929e-07f);
            const int m = m0 + lrow;
            size_t orow;
            if (EPI == 2) {        // X -> XR
                const int b = m >> 13, rr = (m >> 3) & 1023, gg = m & 7;
                orow = (((size_t)b * G_ + gg) << 10) + rr;
            } else if (EPI == 3) { // XR -> X
                const int b = m >> 13, gg = (m >> 10) & 7, rr = m & 1023;
                orow = ((((size_t)b << 10) + rr) << 3) + gg;
            } else {
                orow = m;
            }
#pragma unroll
            for (int nt = 0; nt < 3; ++nt) {
                const int n = w * 48 + nt * 16 + l15;
                const float v = acc[mt][nt][r2] * inv * gvec[n];
                if (EPI == 4) ((float*)Cp)[orow * E_ + n] = v;
                else          ((unsigned short*)Cp)[orow * E_ + n] = f2bf(v);
            }
        }
    }
}

// ---- Feature-group attention. QKV fused buffer [M][576]: Q=0, K=+192, V=+384.
__global__ __launch_bounds__(256)
void k_attn1(const unsigned short* __restrict__ QKV, unsigned short* __restrict__ T)
{
    const int wave = blockIdx.x * 4 + (threadIdx.x >> 6);
    const int lane = threadIdx.x & 63;
    const int seq = wave / H_;
    const int h = wave % H_;
    const int i = lane >> 3, j = lane & 7;
    const unsigned short* qp = QKV + ((size_t)(seq * G_ + i)) * 576 + h * D_;
    const unsigned short* kp = QKV + ((size_t)(seq * G_ + j)) * 576 + 192 + h * D_;
    float s = 0.f;
#pragma unroll
    for (int d8 = 0; d8 < 4; ++d8) {
        u16x8 qv = *(const u16x8*)(qp + d8 * 8);
        u16x8 kv = *(const u16x8*)(kp + d8 * 8);
#pragma unroll
        for (int e = 0; e < 8; ++e) s += bf2f(qv[e]) * bf2f(kv[e]);
    }
    float mx = s;
#pragma unroll
    for (int off = 1; off < 8; off <<= 1) mx = fmaxf(mx, __shfl_xor(mx, off));
    float p = __expf(s - mx);
    float sum = p;
#pragma unroll
    for (int off = 1; off < 8; off <<= 1) sum += __shfl_xor(sum, off);
    p /= sum;
    const int base = lane & ~7;
    float o0 = 0.f, o1 = 0.f, o2 = 0.f, o3 = 0.f;
#pragma unroll
    for (int jj = 0; jj < 8; ++jj) {
        float pj = __shfl(p, base + jj);
        ushort4 vv = *(const ushort4*)(QKV + ((size_t)(seq * G_ + jj)) * 576 + 384 + h * D_ + j * 4);
        o0 += pj * bf2f(vv.x); o1 += pj * bf2f(vv.y);
        o2 += pj * bf2f(vv.z); o3 += pj * bf2f(vv.w);
    }
    ushort4 ov; ov.x = f2bf(o0); ov.y = f2bf(o1); ov.z = f2bf(o2); ov.w = f2bf(o3);
    *(ushort4*)(T + ((size_t)(seq * G_ + i)) * E_ + h * D_ + j * 4) = ov;
}

// ---- Row attention, MFMA flash, exp2 domain (log2e folded into Wq2).
// XCD-chunked swizzle: all 16 q-tiles of one (s,h) land on the same XCD.
__global__ __launch_bounds__(256)
void k_attn2(const unsigned short* __restrict__ QKV, unsigned short* __restrict__ T,
             const int* __restrict__ sep_ptr)
{
    __shared__ unsigned short K_lds[64][40];
    __shared__ unsigned short Vt_lds[32][74];
    __shared__ unsigned short P_lds[4][16][76];

    const int sep = *sep_ptr;
    const int bid = blockIdx.x;
    const int sh = ((bid >> 7) << 3) | (bid & 7);   // same sh => same bid%8 => same XCD
    const int qtile = (bid >> 3) & 15;
    const int s = sh / H_, h = sh % H_;
    const int q0 = qtile * 64;

    const int tid = threadIdx.x;
    const int w = tid >> 6;
    const int lane = tid & 63;
    const int l15 = lane & 15;
    const int g = lane >> 4;

    const int qrow = q0 + w * 16 + l15;
    u16x8 qf = *(const u16x8*)(QKV + ((size_t)s * R_ + qrow) * 576 + h * D_ + g * 8);

    const bool lo = (q0 < sep);
    const bool hi = (q0 + 64 > sep);
    const int npass = (lo && hi) ? 2 : 1;
    const int nChunk = (sep + 63) >> 6;

    const int skey = tid >> 2;
    const int sg   = tid & 3;

    for (int pass = 0; pass < npass; ++pass) {
        const int hk = (pass == 0) ? (lo ? h : 0) : 0;
        const unsigned short* Kb = QKV + (size_t)s * R_ * 576 + 192 + hk * D_;
        const unsigned short* Vb = QKV + (size_t)s * R_ * 576 + 384 + hk * D_;

        float mrun = -1e30f, lrun = 0.f;
        f32x4 o0 = {0.f, 0.f, 0.f, 0.f};
        f32x4 o1 = {0.f, 0.f, 0.f, 0.f};

        for (int kc = 0; kc < nChunk; ++kc) {
            const int kbase = kc * 64;
            const bool full = (kbase + 64 <= sep);
            __syncthreads();
            *(u16x8*)&K_lds[skey][sg * 8] =
                *(const u16x8*)(Kb + (size_t)(kbase + skey) * 576 + sg * 8);
            {
                const int d0 = sg * 8;
                u16x8 vv = *(const u16x8*)(Vb + (size_t)(kbase + skey) * 576 + d0);
#pragma unroll
                for (int e = 0; e < 8; ++e) Vt_lds[d0 + e][skey] = vv[e];
            }
            __syncthreads();

            f32x4 sc[4];
            const f32x4 zf = {0.f, 0.f, 0.f, 0.f};
#pragma unroll
            for (int t = 0; t < 4; ++t) {
                bf16x8 a = *(const bf16x8*)&K_lds[t * 16 + l15][g * 8];
                sc[t] = __builtin_amdgcn_mfma_f32_16x16x32_bf16(a, (bf16x8)qf, zf, 0, 0, 0);
            }
            if (!full) {
#pragma unroll
                for (int t = 0; t < 4; ++t)
#pragma unroll
                    for (int r = 0; r < 4; ++r)
                        if (kbase + t * 16 + g * 4 + r >= sep) sc[t][r] = -1e30f;
            }
            float mx = sc[0][0];
#pragma unroll
            for (int t = 0; t < 4; ++t)
#pragma unroll
                for (int r = 0; r < 4; ++r) mx = fmaxf(mx, sc[t][r]);
            mx = fmaxf(mx, __shfl_xor(mx, 16));
            mx = fmaxf(mx, __shfl_xor(mx, 32));
            const float mnew = fmaxf(mrun, mx);
            const float scale = exp2f(mrun - mnew);
            float psum = 0.f;
#pragma unroll
            for (int t = 0; t < 4; ++t) {
                ushort4 pw;
#pragma unroll
                for (int r = 0; r < 4; ++r) {
                    const float p = exp2f(sc[t][r] - mnew);
                    psum += p;
                    ((unsigned short*)&pw)[r] = f2bf(p);
                }
                *(ushort4*)&P_lds[w][l15][t * 16 + g * 4] = pw;
            }
            psum += __shfl_xor(psum, 16);
            psum += __shfl_xor(psum, 32);
            lrun = lrun * scale + psum;
#pragma unroll
            for (int r = 0; r < 4; ++r) { o0[r] *= scale; o1[r] *= scale; }
#pragma unroll
            for (int ks = 0; ks < 2; ++ks) {
                bf16x8 pb = *(const bf16x8*)&P_lds[w][l15][ks * 32 + g * 8];
                bf16x8 va0 = *(const bf16x8*)&Vt_lds[l15][ks * 32 + g * 8];
                bf16x8 va1 = *(const bf16x8*)&Vt_lds[16 + l15][ks * 32 + g * 8];
                o0 = __builtin_amdgcn_mfma_f32_16x16x32_bf16(va0, pb, o0, 0, 0, 0);
                o1 = __builtin_amdgcn_mfma_f32_16x16x32_bf16(va1, pb, o1, 0, 0, 0);
            }
            mrun = mnew;
        }

        const bool valid = (npass == 1) || (pass == 0 ? (qrow < sep) : (qrow >= sep));
        if (valid) {
            const float inv = 1.f / lrun;
            unsigned short* tp = T + ((size_t)s * R_ + qrow) * E_ + h * D_;
            ushort4 v0, v1;
            v0.x = f2bf(o0[0] * inv); v0.y = f2bf(o0[1] * inv);
            v0.z = f2bf(o0[2] * inv); v0.w = f2bf(o0[3] * inv);
            v1.x = f2bf(o1[0] * inv); v1.y = f2bf(o1[1] * inv);
            v1.z = f2bf(o1[2] * inv); v1.w = f2bf(o1[3] * inv);
            *(ushort4*)(tp + g * 4)      = v0;
            *(ushort4*)(tp + 16 + g * 4) = v1;
        }
    }
}

extern "C" void kernel_launch(void* const* d_in, const int* in_sizes, int n_in,
                              void* d_out, int out_size, void* d_ws, size_t ws_size,
                              hipStream_t stream) {
    const float* hidden = (const float*)d_in[0];
    const float* Wq1 = (const float*)d_in[1];
    const float* Wk1 = (const float*)d_in[2];
    const float* Wv1 = (const float*)d_in[3];
    const float* Wo1 = (const float*)d_in[4];
    const float* Wq2 = (const float*)d_in[5];
    const float* Wk2 = (const float*)d_in[6];
    const float* Wv2 = (const float*)d_in[7];
    const float* Wo2 = (const float*)d_in[8];
    const float* W1  = (const float*)d_in[9];
    const float* W2  = (const float*)d_in[10];
    const float* g1  = (const float*)d_in[11];
    const float* g2  = (const float*)d_in[12];
    const float* g3  = (const float*)d_in[13];
    const int*   sep = (const int*)d_in[14];

    float* Xout = (float*)d_out;                    // final f32 X-layout output
    unsigned short* ws = (unsigned short*)d_ws;
    unsigned short* QKVb = ws;                      // [M][576] bf16 (aliases H1 [M][384])
    unsigned short* Tb   = QKVb + (size_t)M_ * 576;
    unsigned short* Ynb  = Tb + NBUF;               // rms-g1 output, XR layout
    unsigned short* Xcb  = Ynb + NBUF;              // rms-g2 output, X layout
    unsigned short* Xb   = Xcb + NBUF;              // inter-layer residual (layers 0-2)
    unsigned short* Wt   = Xb + NBUF;
    unsigned short* H1b  = QKVb;

    const dim3 blk(256);
    const dim3 gQKV(M_ / 64, 3);
    const dim3 gW1(M_ / 64, 2);
    const dim3 g1x(M_ / 64, 1);
    const dim3 gA1((4096 * H_) / 4);
    const dim3 gA2(32 * H_ * 16);

    k_convw_all<<<dim3(432 * L_), blk, 0, stream>>>(Wq1, Wk1, Wv1, Wo1, Wq2, Wk2, Wv2, Wo2, W1, W2, Wt);

    for (int i = 0; i < L_; ++i) {
        unsigned short* wl = Wt + (size_t)i * WPL;
        const unsigned short* wqkv1 = wl;
        const unsigned short* wo1   = wl + 3 * (size_t)E_ * E_;
        const unsigned short* wqkv2 = wl + 4 * (size_t)E_ * E_;
        const unsigned short* wo2   = wl + 7 * (size_t)E_ * E_;
        const unsigned short* w1    = wl + 8 * (size_t)E_ * E_;
        const unsigned short* w2    = wl + 8 * (size_t)E_ * E_ + (size_t)E_ * F_;
        const float* g1i = g1 + (size_t)i * E_;
        const float* g2i = g2 + (size_t)i * E_;
        const float* g3i = g3 + (size_t)i * E_;

        // --- feature-group attention block ---
        if (i == 0)
            k_gemm_mfma<false, false, 0><<<gQKV, blk, 0, stream>>>(hidden, wqkv1, nullptr, nullptr, QKVb, 576, E_);
        else
            k_gemm_mfma<true, false, 0><<<gQKV, blk, 0, stream>>>(Xb, wqkv1, nullptr, nullptr, QKVb, 576, E_);
        k_attn1<<<gA1, blk, 0, stream>>>(QKVb, Tb);
        if (i == 0)
            k_gemm_mfma<true, false, 2><<<g1x, blk, 0, stream>>>(Tb, wo1, hidden, g1i, Ynb, E_, E_);
        else
            k_gemm_mfma<true, true, 2><<<g1x, blk, 0, stream>>>(Tb, wo1, Xb, g1i, Ynb, E_, E_);
        // --- row attention block ---
        k_gemm_mfma<true, false, 0><<<gQKV, blk, 0, stream>>>(Ynb, wqkv2, nullptr, nullptr, QKVb, 576, E_);
        k_attn2<<<gA2, blk, 0, stream>>>(QKVb, Tb, sep);
        k_gemm_mfma<true, true, 3><<<g1x, blk, 0, stream>>>(Tb, wo2, Ynb, g2i, Xcb, E_, E_);
        // --- MLP block ---
        k_gemm_mfma<true, false, 1><<<gW1, blk, 0, stream>>>(Xcb, w1, nullptr, nullptr, H1b, F_, E_);
        if (i == L_ - 1)
            k_gemm_mfma<true, true, 4><<<g1x, blk, 0, stream>>>(H1b, w2, Xcb, g3i, Xout, E_, F_);
        else
            k_gemm_mfma<true, true, 5><<<g1x, blk, 0, stream>>>(H1b, w2, Xcb, g3i, Xb, E_, F_);
    }
}